// Round 1
// baseline (870.813 us; speedup 1.0000x reference)
//
#include <hip/hip_runtime.h>
#include <stdint.h>

#define NTOK 64
#define CDIM 384
#define NH   12
#define HD   32
#define SCALE 0.17677669529663687f  // 32^-0.5

typedef __attribute__((ext_vector_type(8))) short short8;
typedef __attribute__((ext_vector_type(4))) float floatx4;

__device__ __forceinline__ unsigned short f2bf(float f) {
    union { float f; unsigned u; } v; v.f = f;
    unsigned r = (v.u + 0x7fffu + ((v.u >> 16) & 1u)) >> 16;  // RNE
    return (unsigned short)r;
}

// ---------- prep: transpose weights to bf16 (W^T rows = output cols, contiguous K) ----------
__global__ void prep_weights(const float* __restrict__ qkv_w,
                             const float* __restrict__ proj_w,
                             unsigned short* __restrict__ qkv_wt,
                             unsigned short* __restrict__ proj_wt) {
    int i = blockIdx.x * blockDim.x + threadIdx.x;
    const int nq = 1152 * 384;
    const int np = 384 * 384;
    if (i < nq) {
        int r = i / 384, c = i - r * 384;          // qkv_wt[r][c] = qkv_w[c][r]
        qkv_wt[i] = f2bf(qkv_w[c * 1152 + r]);
    } else if (i < nq + np) {
        int o = i - nq;
        int r = o / 384, c = o - r * 384;
        proj_wt[o] = f2bf(proj_w[c * 384 + r]);
    }
}

// ---------- prep: relative-position bias table bt[h][i][j], 12x64x64 fp32 ----------
__global__ void prep_bias(const float* __restrict__ w1, const float* __restrict__ b1,
                          const float* __restrict__ w2, const float* __restrict__ b2,
                          float* __restrict__ bt) {
    int t = blockIdx.x * blockDim.x + threadIdx.x;  // 4096 threads
    int i = t >> 6, j = t & 63;
    float r0 = (float)((i >> 4) - (j >> 4));
    float r1 = (float)(((i >> 2) & 3) - ((j >> 2) & 3));
    float r2 = (float)((i & 3) - (j & 3));
    float acc[NH];
#pragma unroll
    for (int h = 0; h < NH; ++h) acc[h] = b2[h];
    for (int u = 0; u < 64; ++u) {
        float hv = r0 * w1[u] + r1 * w1[64 + u] + r2 * w1[128 + u] + b1[u];
        hv = fmaxf(hv, 0.f);
#pragma unroll
        for (int h = 0; h < NH; ++h) acc[h] += hv * w2[u * NH + h];
    }
    for (int h = 0; h < NH; ++h) bt[(h << 12) + (i << 6) + j] = acc[h];
}

// ---------- fused window attention: one block = one window ----------
#define XP  392   // xs/ao row stride (384+8): stride%32dw breaks LDS bank alias
#define QKP 40    // q/k row stride (32+8)
#define VTP 72    // vT row stride (64+8)
#define PBP 72    // P row stride (64+8)

__launch_bounds__(256, 1)
__global__ void win_attn(const float* __restrict__ x,
                         const unsigned short* __restrict__ qkv_wt,
                         const float* __restrict__ qkv_b,
                         const unsigned short* __restrict__ proj_wt,
                         const float* __restrict__ proj_b,
                         const float* __restrict__ bt,
                         float* __restrict__ out) {
    __shared__ unsigned short xs[64 * XP];          // x window, bf16       50176 B
    __shared__ unsigned short ao[64 * XP];          // attn out, bf16       50176 B
    __shared__ unsigned short qls[2][64 * QKP];     // q per head-pair      10240 B
    __shared__ unsigned short kls[2][64 * QKP];     // k per head-pair      10240 B
    __shared__ unsigned short vts[2][32 * VTP];     // v^T per head-pair     9216 B
    __shared__ unsigned short pbs[2][64 * PBP];     // P per head-pair      18432 B
                                                    // total 148480 B -> 1 block/CU
    const int tid  = threadIdx.x;
    const int lane = tid & 63;
    const int w    = tid >> 6;     // wave 0..3
    const int l15  = lane & 15;
    const int quad = lane >> 4;
    const int b    = blockIdx.x;

    // ---- stage x -> bf16 LDS (coalesced float4) ----
    const float* xb = x + (size_t)b * (64 * 384);
    for (int it = 0; it < 24; ++it) {
        int idx = it * 256 + tid;
        int row = idx / 96;                          // 96 float4 per row
        int c4  = idx - row * 96;
        const float4 v = *reinterpret_cast<const float4*>(xb + row * 384 + c4 * 4);
        uint2 pk;
        pk.x = (unsigned)f2bf(v.x) | ((unsigned)f2bf(v.y) << 16);
        pk.y = (unsigned)f2bf(v.z) | ((unsigned)f2bf(v.w) << 16);
        *reinterpret_cast<uint2*>(&xs[row * XP + c4 * 4]) = pk;
    }
    __syncthreads();

    const int hh = w >> 1;   // which head of the pair this wave's QKV N-tiles serve
    const int d2 = w & 1;    // which 16-wide d-half
    float rs[2][4];          // 1/rowsum carried from softmax to PV epilogue
    const floatx4 zf4 = {0.f, 0.f, 0.f, 0.f};

#pragma unroll 1
    for (int hp = 0; hp < 6; ++hp) {
        // ======== B1: QKV GEMM for heads 2hp, 2hp+1 ========
        // wave w computes q,k,v (s=0,1,2) for head hh, d-half d2; all 4 M-tiles.
        floatx4 acc[3][4];
#pragma unroll
        for (int j = 0; j < 3; ++j)
#pragma unroll
            for (int m = 0; m < 4; ++m) acc[j][m] = zf4;

        int colbase[3];
#pragma unroll
        for (int j = 0; j < 3; ++j)
            colbase[j] = j * 384 + (2 * hp + hh) * 32 + d2 * 16;

#pragma unroll
        for (int kk = 0; kk < 12; ++kk) {
            short8 a[4];
#pragma unroll
            for (int m = 0; m < 4; ++m)
                a[m] = *reinterpret_cast<const short8*>(
                    &xs[(16 * m + l15) * XP + kk * 32 + quad * 8]);
#pragma unroll
            for (int j = 0; j < 3; ++j) {
                const short8 bf = *reinterpret_cast<const short8*>(
                    qkv_wt + (size_t)(colbase[j] + l15) * 384 + kk * 32 + quad * 8);
#pragma unroll
                for (int m = 0; m < 4; ++m)
                    acc[j][m] = __builtin_amdgcn_mfma_f32_16x16x32_bf16(a[m], bf, acc[j][m], 0, 0, 0);
            }
        }
        // epilogue: +bias, q/k row-major, v transposed (packed 8B stores)
#pragma unroll
        for (int j = 0; j < 3; ++j) {
            const float bc = qkv_b[colbase[j] + l15];
            if (j < 2) {
                unsigned short* dst = (j == 0) ? qls[hh] : kls[hh];
#pragma unroll
                for (int m = 0; m < 4; ++m)
#pragma unroll
                    for (int r = 0; r < 4; ++r) {
                        int tok = 16 * m + quad * 4 + r;
                        dst[tok * QKP + d2 * 16 + l15] = f2bf(acc[j][m][r] + bc);
                    }
            } else {
#pragma unroll
                for (int m = 0; m < 4; ++m) {
                    uint2 pk;
                    pk.x = (unsigned)f2bf(acc[2][m][0] + bc) | ((unsigned)f2bf(acc[2][m][1] + bc) << 16);
                    pk.y = (unsigned)f2bf(acc[2][m][2] + bc) | ((unsigned)f2bf(acc[2][m][3] + bc) << 16);
                    *reinterpret_cast<uint2*>(
                        &vts[hh][(d2 * 16 + l15) * VTP + 16 * m + quad * 4]) = pk;
                }
            }
        }
        __syncthreads();

        // ======== B2: S = qk^T*scale + bias, online row softmax ========
        // wave w owns S row-block w (rows 16w..16w+15) for both heads.
#pragma unroll
        for (int hi = 0; hi < 2; ++hi) {
            const int h = 2 * hp + hi;
            const short8 aq = *reinterpret_cast<const short8*>(
                &qls[hi][(16 * w + l15) * QKP + quad * 8]);
            floatx4 s4[4];
#pragma unroll
            for (int c = 0; c < 4; ++c) {
                const short8 bk = *reinterpret_cast<const short8*>(
                    &kls[hi][(16 * c + l15) * QKP + quad * 8]);
                s4[c] = __builtin_amdgcn_mfma_f32_16x16x32_bf16(aq, bk, zf4, 0, 0, 0);
            }
            const float* bth = bt + ((size_t)h << 12);
#pragma unroll
            for (int r = 0; r < 4; ++r) {
                const int n = 16 * w + quad * 4 + r;   // C-layout row
#pragma unroll
                for (int c = 0; c < 4; ++c)
                    s4[c][r] = s4[c][r] * SCALE + bth[(n << 6) + 16 * c + l15];
                float m0 = fmaxf(fmaxf(s4[0][r], s4[1][r]), fmaxf(s4[2][r], s4[3][r]));
#pragma unroll
                for (int sh = 1; sh < 16; sh <<= 1) m0 = fmaxf(m0, __shfl_xor(m0, sh, 16));
                float p0 = 0.f;
#pragma unroll
                for (int c = 0; c < 4; ++c) {
                    float p = __expf(s4[c][r] - m0);
                    s4[c][r] = p;
                    p0 += p;
                }
#pragma unroll
                for (int sh = 1; sh < 16; sh <<= 1) p0 += __shfl_xor(p0, sh, 16);
                rs[hi][r] = 1.f / p0;
#pragma unroll
                for (int c = 0; c < 4; ++c)           // unnormalized P (<=1), bf16
                    pbs[hi][n * PBP + 16 * c + l15] = f2bf(s4[c][r]);
            }
        }
        __syncthreads();

        // ======== B3: O = P @ V, normalize, assemble into ao ========
#pragma unroll
        for (int hi = 0; hi < 2; ++hi) {
            const int h = 2 * hp + hi;
            short8 ap[2];
#pragma unroll
            for (int kk = 0; kk < 2; ++kk)
                ap[kk] = *reinterpret_cast<const short8*>(
                    &pbs[hi][(16 * w + l15) * PBP + kk * 32 + quad * 8]);
#pragma unroll
            for (int t = 0; t < 2; ++t) {
                floatx4 oacc = zf4;
#pragma unroll
                for (int kk = 0; kk < 2; ++kk) {
                    const short8 bv = *reinterpret_cast<const short8*>(
                        &vts[hi][(16 * t + l15) * VTP + kk * 32 + quad * 8]);
                    oacc = __builtin_amdgcn_mfma_f32_16x16x32_bf16(ap[kk], bv, oacc, 0, 0, 0);
                }
#pragma unroll
                for (int r = 0; r < 4; ++r) {
                    int tok = 16 * w + quad * 4 + r;
                    ao[tok * XP + h * 32 + 16 * t + l15] = f2bf(oacc[r] * rs[hi][r]);
                }
            }
        }
        __syncthreads();
    }

    // ======== proj: out = ao(64x384) @ proj_w + proj_b ========
    float* ob = out + (size_t)b * (64 * 384);
#pragma unroll 1
    for (int pass = 0; pass < 2; ++pass) {
        const int ntb = pass * 12 + w * 3;   // 3 N-tiles per wave per pass
        floatx4 acc2[3][4];
#pragma unroll
        for (int j = 0; j < 3; ++j)
#pragma unroll
            for (int m = 0; m < 4; ++m) acc2[j][m] = zf4;

#pragma unroll
        for (int kk = 0; kk < 12; ++kk) {
            short8 a2[4];
#pragma unroll
            for (int m = 0; m < 4; ++m)
                a2[m] = *reinterpret_cast<const short8*>(
                    &ao[(16 * m + l15) * XP + kk * 32 + quad * 8]);
#pragma unroll
            for (int j = 0; j < 3; ++j) {
                const short8 bf = *reinterpret_cast<const short8*>(
                    proj_wt + (size_t)((ntb + j) * 16 + l15) * 384 + kk * 32 + quad * 8);
#pragma unroll
                for (int m = 0; m < 4; ++m)
                    acc2[j][m] = __builtin_amdgcn_mfma_f32_16x16x32_bf16(a2[m], bf, acc2[j][m], 0, 0, 0);
            }
        }
#pragma unroll
        for (int j = 0; j < 3; ++j) {
            const int col = (ntb + j) * 16 + l15;
            const float pbias = proj_b[col];
#pragma unroll
            for (int m = 0; m < 4; ++m)
#pragma unroll
                for (int r = 0; r < 4; ++r)
                    ob[(16 * m + quad * 4 + r) * 384 + col] = acc2[j][m][r] + pbias;
        }
    }
}

extern "C" void kernel_launch(void* const* d_in, const int* in_sizes, int n_in,
                              void* d_out, int out_size, void* d_ws, size_t ws_size,
                              hipStream_t stream) {
    const float* x      = (const float*)d_in[0];
    const float* qkv_w  = (const float*)d_in[1];
    const float* qkv_b  = (const float*)d_in[2];
    const float* proj_w = (const float*)d_in[3];
    const float* proj_b = (const float*)d_in[4];
    const float* mlp_w1 = (const float*)d_in[5];
    const float* mlp_b1 = (const float*)d_in[6];
    const float* mlp_w2 = (const float*)d_in[7];
    const float* mlp_b2 = (const float*)d_in[8];
    float* out = (float*)d_out;

    // workspace layout (re-written every launch; harness poisons ws)
    unsigned short* qkv_wt  = (unsigned short*)d_ws;              // 1152*384 bf16
    unsigned short* proj_wt = qkv_wt + 1152 * 384;                // 384*384 bf16
    float*          bt      = (float*)(proj_wt + 384 * 384);      // 12*64*64 fp32

    prep_weights<<<2304, 256, 0, stream>>>(qkv_w, proj_w, qkv_wt, proj_wt);
    prep_bias<<<16, 256, 0, stream>>>(mlp_w1, mlp_b1, mlp_w2, mlp_b2, bt);
    win_attn<<<2048, 256, 0, stream>>>(x, qkv_wt, qkv_b, proj_wt, proj_b, bt, out);
}